// Round 2
// baseline (347.857 us; speedup 1.0000x reference)
//
#include <hip/hip_runtime.h>

#define NN   2048
#define ROWS 128          // rows per block = threads per block (2 waves)
#define CHK  64           // chunk width (columns per LDS tile pass)
#define WARM 64           // warm-up steps: carry error attenuated by prod|sin| ~ e^-40
#define SEGS 8
#define STR  (CHK + 1)    // tile stride 65: +1 spill slot AND odd stride (bank-friendly)

// Chain (exact, descending k):
//   a = c_{2047} x[2047] - s_{2047} x[0];  t0 = s_{2047} x[2047] + c_{2047} x[0]
//   for k = 2046..1:  y[k+1] = s_k x[k] + c_k a;  a = c_k x[k] - s_k a
//   y[1] = s_0 t0 + c_0 a;  y[0] = c_0 t0 - s_0 a
// Segment s owns steps [1+256s, 256+256s] (seg 7: ..2046), entered via a 64-step
// warm-up with a=0 (seg 7 enters exactly). All global I/O staged through an
// in-place LDS tile for full coalescing.
__global__ __launch_bounds__(ROWS) void ring_givens_seg(
        const float* __restrict__ x,
        const float* __restrict__ angles,
        float* __restrict__ y) {
    __shared__ float  tile[ROWS * STR];   // 33,280 B
    __shared__ float2 cs[336];            //  2,688 B  -> 4 blocks/CU, 8 waves/CU

    const int tid    = threadIdx.x;
    const int seg    = blockIdx.x & (SEGS - 1);
    const int rowBlk = blockIdx.x >> 3;
    const int row0   = rowBlk * ROWS;

    const int k_lo  = 1 + seg * 256;
    const int k_hi  = (seg == SEGS - 1) ? (NN - 2) : (k_lo + 255);
    const int wk_hi = (seg == SEGS - 1) ? (NN - 2) : (k_hi + WARM);

    // per-segment (c,s) table, k in [k_lo, wk_hi]
    for (int k = k_lo + tid; k <= wk_hi; k += ROWS) {
        float s, c;
        sincosf(angles[k], &s, &c);
        cs[k - k_lo] = make_float2(c, s);
    }

    const long grow = row0 + tid;
    const float* __restrict__ xr  = x + grow * NN;
    float* __restrict__       yrp = y + grow * NN;

    float a = 0.f;          // warm-up entry
    float x0e = 0.f, xle = 0.f;
    if (seg == SEGS - 1) {  // exact entry: a_{2047}
        float sl, cl;
        sincosf(angles[NN - 1], &sl, &cl);
        float xl = xr[NN - 1], x0 = xr[0];
        a = cl * xl - sl * x0;
    } else if (seg == 0) {  // prefetch for the step-0 epilogue
        x0e = xr[0];
        xle = xr[NN - 1];
    }

    const int cc   = tid & (CHK - 1);  // fixed column within chunk for staging
    const int rr0  = tid >> 6;         // 0 or 1: starting row for staging
    const int base = tid * STR;

    // chunks descend so the carry flows k = wk_hi .. k_lo
    for (int m = (wk_hi - k_lo) / CHK; m >= 0; --m) {
        const int c_lo = k_lo + m * CHK;
        const int c_hi = min(wk_hi, c_lo + CHK - 1);
        const int Cc   = c_hi - c_lo + 1;

        __syncthreads();   // previous chunk's tile reads complete
        if (cc < Cc) {     // coalesced load: x[row0+rr][c_lo+cc] -> tile[rr][cc]
            const float* xp = x + (long)(row0 + rr0) * NN + c_lo + cc;
            #pragma unroll
            for (int rr = rr0; rr < ROWS; rr += 2) {
                tile[rr * STR + cc] = *xp;
                xp += 2 * NN;
            }
        }
        __syncthreads();

        if (c_lo > k_hi) {
            // warm-up chunk: update carry only, no y
            #pragma unroll 8
            for (int k = c_hi; k >= c_lo; --k) {
                float xv = tile[base + (k - c_lo)];
                float2 q = cs[k - k_lo];
                a = q.x * xv - q.y * a;
            }
        } else {
            // main chunk: in-place — step k reads slot p=k-c_lo, writes y into p+1
            #pragma unroll 8
            for (int k = c_hi; k >= c_lo; --k) {
                int p = k - c_lo;
                float xv = tile[base + p];
                float2 q = cs[k - k_lo];
                tile[base + p + 1] = q.y * xv + q.x * a;
                a = q.x * xv - q.y * a;
            }
            __syncthreads();
            if (cc < Cc) {  // coalesced store: tile[rr][1+cc] -> y[row0+rr][c_lo+1+cc]
                float* yp = y + (long)(row0 + rr0) * NN + c_lo + 1 + cc;
                #pragma unroll
                for (int rr = rr0; rr < ROWS; rr += 2) {
                    *yp = tile[rr * STR + 1 + cc];
                    yp += 2 * NN;
                }
            }
        }
    }

    if (seg == 0) {  // step 0: uses t0 (from step 2047) and a = a_1
        float s0, c0, sl, cl;
        sincosf(angles[0], &s0, &c0);
        sincosf(angles[NN - 1], &sl, &cl);
        float t0 = sl * xle + cl * x0e;
        yrp[1] = s0 * t0 + c0 * a;
        yrp[0] = c0 * t0 - s0 * a;
    }
}

extern "C" void kernel_launch(void* const* d_in, const int* in_sizes, int n_in,
                              void* d_out, int out_size, void* d_ws, size_t ws_size,
                              hipStream_t stream) {
    const float* x      = (const float*)d_in[0];
    const float* angles = (const float*)d_in[1];
    float* y            = (float*)d_out;

    const int B       = in_sizes[0] / NN;     // 16384
    const int rowBlks = B / ROWS;             // 128
    const int grid    = rowBlks * SEGS;       // 1024 blocks
    hipLaunchKernelGGL(ring_givens_seg, dim3(grid), dim3(ROWS), 0, stream,
                       x, angles, y);
}